// Round 1
// baseline (255.055 us; speedup 1.0000x reference)
//
#include <hip/hip_runtime.h>
#include <math.h>

#define NB 16      // batch
#define NC 80      // classes
#define HH 128
#define WW 128
#define NM 32      // boxes per batch
#define IMG 512.0f

// output layout (float offsets)
#define OFF_VALUES 0
#define OFF_IDXS   262144
#define OFF_BBOX   524288
#define OFF_KEEP   1572864
#define OFF_PFL    1835008
#define OFF_SZL    1835009
#define OFF_OSL    1835010
#define OFF_GTHM   1835011

struct BoxParam { float ci0, ci1, inv2sig; int cls; };

__device__ __forceinline__ float smooth_l1(float p, float g) {
    float d = fabsf(p - g);
    return (d < 1.0f) ? 0.5f * d * d : d - 0.5f;
}

// ---------------- kernel 1: box params + per-batch class CSR ----------------
__global__ void setup_kernel(const float* __restrict__ gtb, const int* __restrict__ gtc,
                             BoxParam* __restrict__ bp, int* __restrict__ csr_start,
                             int* __restrict__ csr_order, float* __restrict__ out) {
    int t = threadIdx.x;  // blockDim = 512
    if (t < NB * NM) {
        const float* g = gtb + t * 4;
        float x1 = g[0], y1 = g[1], x2 = g[2], y2 = g[3];
        float cx = (x1 + x2) * 0.5f, cy = (y1 + y2) * 0.5f;
        float c0 = floorf(cx * 0.25f);   // cxy / DS, DS=4 (exact)
        float c1 = floorf(cy * 0.25f);
        float w = x2 - x1, h = y2 - y1;
        float sigma = fmaxf(w, h) * 0.25f;     // sizes.max(-1)/DS
        BoxParam p;
        p.ci0 = c0; p.ci1 = c1;
        p.inv2sig = 1.0f / (2.0f * sigma);
        p.cls = gtc[t];
        bp[t] = p;
    }
    if (t == 0) out[OFF_PFL] = 0.0f;   // zero focal accumulator (kernel order on stream serializes)
    __syncthreads();
    if (t < NB) {
        int b = t;
        int base = b * NM;
        int cnt[NC + 1];
        for (int c = 0; c <= NC; ++c) cnt[c] = 0;
        for (int m = 0; m < NM; ++m) cnt[bp[base + m].cls + 1]++;
        for (int c = 0; c < NC; ++c) cnt[c + 1] += cnt[c];
        int* st = csr_start + b * (NC + 1);
        for (int c = 0; c <= NC; ++c) st[c] = cnt[c];
        int pos[NC];
        for (int c = 0; c < NC; ++c) pos[c] = cnt[c];
        for (int m = 0; m < NM; ++m) {
            int c = bp[base + m].cls;
            csr_order[base + pos[c]++] = m;
        }
    }
}

// ---------------- kernel 2: fused NMS + gt_hm + focal + bbox decode ----------------
// grid: NB*64 blocks (tile = 4 rows x 64 cols), block = 256 threads (1 px/thread)
__launch_bounds__(256)
__global__ void main_kernel(const float* __restrict__ hm, const float* __restrict__ sz,
                            const float* __restrict__ osr, const BoxParam* __restrict__ bp,
                            const int* __restrict__ csr_start, const int* __restrict__ csr_order,
                            float* __restrict__ out) {
    int blk = blockIdx.x;
    int b = blk >> 6;
    int tle = blk & 63;
    int i0 = (tle >> 1) * 4;
    int j0 = (tle & 1) * 64;
    int tid = threadIdx.x;
    int i = i0 + (tid >> 6);
    int j = j0 + (tid & 63);

    __shared__ int   s_start[NC + 1];
    __shared__ float s_box[NM][3];   // ci0, ci1, inv2sig
    __shared__ int   s_ord[NM];
    for (int k = tid; k < NC + 1; k += 256) s_start[k] = csr_start[b * (NC + 1) + k];
    if (tid < NM) {
        BoxParam p = bp[b * NM + tid];
        s_box[tid][0] = p.ci0; s_box[tid][1] = p.ci1; s_box[tid][2] = p.inv2sig;
        s_ord[tid] = csr_order[b * NM + tid];
    }
    __syncthreads();

    const float fi = (float)i, fj = (float)j;
    float best = -1.0f; int bidx = 0;
    float facc = 0.0f;
    const float* hmb = hm + (size_t)b * NC * HH * WW;
    float* gout = out + OFF_GTHM + (size_t)b * NC * HH * WW;

    int ilo = (i > 0) ? i - 1 : i, ihi = (i < HH - 1) ? i + 1 : i;
    int jlo = (j > 0) ? j - 1 : j, jhi = (j < WW - 1) ? j + 1 : j;

    for (int c = 0; c < NC; ++c) {
        const float* plane = hmb + (size_t)c * (HH * WW);
        float h = plane[i * WW + j];
        float mx = h;
        #pragma unroll
        for (int ii = 0; ii < 3; ++ii) {
            int ri = i - 1 + ii;
            if (ri < ilo || ri > ihi) continue;
            for (int jj = jlo; jj <= jhi; ++jj)
                mx = fmaxf(mx, plane[ri * WW + jj]);
        }
        float p = (h >= mx) ? h : 0.0f;
        if (p > best) { best = p; bidx = c; }

        // gt_hm: max over boxes of this class
        float g = 0.0f;
        int s0 = s_start[c], s1 = s_start[c + 1];
        for (int k = s0; k < s1; ++k) {
            int m = s_ord[k];
            float d0 = fi - s_box[m][0];
            float d1 = fj - s_box[m][1];
            float d2 = d0 * d0 + d1 * d1;
            g = fmaxf(g, __expf(-d2 * s_box[m][2]));
        }
        gout[(size_t)c * (HH * WW) + i * WW + j] = g;

        // focal term
        float om = 1.0f - g;
        float om2 = om * om, om4 = om2 * om2;
        float g2 = g * g, g4 = g2 * g2;
        float oh = 1.0f - h;
        facc += om4 * h * h * log1pf(-h) + g4 * oh * oh * logf(h);
    }

    // per-pixel outputs
    int pix = (b * HH + i) * WW + j;
    out[OFF_VALUES + pix] = best;
    out[OFF_IDXS + pix]   = (float)bidx;
    out[OFF_KEEP + pix]   = (best > 0.0f) ? 1.0f : 0.0f;

    const float* szb = sz + (size_t)b * 2 * HH * WW;
    const float* osb = osr + (size_t)b * 2 * HH * WW;
    int pij = i * WW + j;
    float s0v = szb[pij], s1v = szb[HH * WW + pij];
    float o0 = osb[pij],  o1 = osb[HH * WW + pij];
    float c0 = fi * 4.0f + o0, c1 = fj * 4.0f + o1;
    float4 bbox;
    bbox.x = fminf(fmaxf(c0 - s0v * 0.5f, 0.0f), IMG);
    bbox.y = fminf(fmaxf(c1 - s1v * 0.5f, 0.0f), IMG);
    bbox.z = fminf(fmaxf(c0 + s0v * 0.5f, 0.0f), IMG);
    bbox.w = fminf(fmaxf(c1 + s1v * 0.5f, 0.0f), IMG);
    reinterpret_cast<float4*>(out + OFF_BBOX)[pix] = bbox;

    // focal reduce: wave shuffle then LDS
    #pragma unroll
    for (int off = 32; off > 0; off >>= 1) facc += __shfl_down(facc, off);
    __shared__ float s_red[4];
    if ((tid & 63) == 0) s_red[tid >> 6] = facc;
    __syncthreads();
    if (tid == 0) {
        float tot = s_red[0] + s_red[1] + s_red[2] + s_red[3];
        atomicAdd(out + OFF_PFL, -tot);
    }
}

// ---------------- kernel 3: size / offset losses at center cells ----------------
// 1 block, 512 threads: t = b*32 + m. Last-writer-wins dedup per (b, cell).
__global__ void loss_kernel(const float* __restrict__ gtb, const float* __restrict__ sz,
                            const float* __restrict__ osr, float* __restrict__ out) {
    int t = threadIdx.x;
    int b = t >> 5, m = t & 31;
    __shared__ int s_ci[NB * NM];
    const float* g = gtb + t * 4;
    float x1 = g[0], y1 = g[1], x2 = g[2], y2 = g[3];
    float cx = (x1 + x2) * 0.5f, cy = (y1 + y2) * 0.5f;
    float c0f = floorf(cx * 0.25f), c1f = floorf(cy * 0.25f);
    int ci0 = (int)c0f, ci1 = (int)c1f;
    s_ci[t] = ci0 * WW + ci1;
    __syncthreads();

    bool winner = true;
    int mycell = s_ci[t];
    for (int m2 = m + 1; m2 < NM; ++m2)
        if (s_ci[b * NM + m2] == mycell) { winner = false; break; }

    float nloc = 0.0f, szs = 0.0f, oss = 0.0f;
    if (winner) {
        nloc = 1.0f;
        float w = x2 - x1, h = y2 - y1;
        float offx = cx * 0.25f - c0f, offy = cy * 0.25f - c1f;
        size_t pb = (size_t)b * 2 * HH * WW + (size_t)ci0 * WW + ci1;
        float ps0 = sz[pb], ps1 = sz[pb + HH * WW];
        float po0 = osr[pb], po1 = osr[pb + HH * WW];
        szs = smooth_l1(ps0, w) + smooth_l1(ps1, h);
        oss = smooth_l1(po0, offx) + smooth_l1(po1, offy);
    }

    #pragma unroll
    for (int off = 32; off > 0; off >>= 1) {
        nloc += __shfl_down(nloc, off);
        szs  += __shfl_down(szs, off);
        oss  += __shfl_down(oss, off);
    }
    __shared__ float red[8][3];
    int wid = t >> 6;
    if ((t & 63) == 0) { red[wid][0] = nloc; red[wid][1] = szs; red[wid][2] = oss; }
    __syncthreads();
    if (t == 0) {
        float n = 0.0f, ss = 0.0f, os_ = 0.0f;
        for (int w2 = 0; w2 < 8; ++w2) { n += red[w2][0]; ss += red[w2][1]; os_ += red[w2][2]; }
        out[OFF_SZL] = ss / (2.0f * n) / n;
        out[OFF_OSL] = os_ / (2.0f * n) / n;
    }
}

extern "C" void kernel_launch(void* const* d_in, const int* in_sizes, int n_in,
                              void* d_out, int out_size, void* d_ws, size_t ws_size,
                              hipStream_t stream) {
    const float* hm  = (const float*)d_in[0];
    const float* sz  = (const float*)d_in[1];
    const float* osr = (const float*)d_in[2];
    const float* gtb = (const float*)d_in[3];
    const int*   gtc = (const int*)d_in[4];
    float* out = (float*)d_out;

    BoxParam* bp   = (BoxParam*)d_ws;                           // 512 * 16 B = 8192
    int* csr_start = (int*)((char*)d_ws + 8192);                // 16 * 81 * 4 = 5184
    int* csr_order = (int*)((char*)d_ws + 8192 + 5184);         // 512 * 4 = 2048

    setup_kernel<<<1, 512, 0, stream>>>(gtb, gtc, bp, csr_start, csr_order, out);
    main_kernel<<<NB * 64, 256, 0, stream>>>(hm, sz, osr, bp, csr_start, csr_order, out);
    loss_kernel<<<1, 512, 0, stream>>>(gtb, sz, osr, out);
}

// Round 2
// 93.731 us; speedup vs baseline: 2.7211x; 2.7211x over previous
//
#include <hip/hip_runtime.h>
#include <math.h>

#define NB 16      // batch
#define NC 80      // classes
#define HH 128
#define WW 128
#define HW (HH*WW)
#define NPIX (NB*HH*WW)   // 262144
#define NM 32      // boxes per batch
#define IMG 512.0f

// output layout (float offsets)
#define OFF_VALUES 0
#define OFF_IDXS   262144
#define OFF_BBOX   524288
#define OFF_KEEP   1572864
#define OFF_PFL    1835008
#define OFF_SZL    1835009
#define OFF_OSL    1835010
#define OFF_GTHM   1835011

struct BoxParam { float ci0, ci1, inv2sig; int cls; };

__device__ __forceinline__ float smooth_l1(float p, float g) {
    float d = fabsf(p - g);
    return (d < 1.0f) ? 0.5f * d * d : d - 0.5f;
}
__device__ __forceinline__ float fmax3(float a, float b, float c) {
    return fmaxf(fmaxf(a, b), c);
}

// ---------------- kernel 1: box params + per-batch class CSR ----------------
__global__ void setup_kernel(const float* __restrict__ gtb, const int* __restrict__ gtc,
                             BoxParam* __restrict__ bp, int* __restrict__ csr_start,
                             int* __restrict__ csr_order, float* __restrict__ out) {
    int t = threadIdx.x;  // blockDim = 512
    if (t < NB * NM) {
        const float* g = gtb + t * 4;
        float x1 = g[0], y1 = g[1], x2 = g[2], y2 = g[3];
        float cx = (x1 + x2) * 0.5f, cy = (y1 + y2) * 0.5f;
        float c0 = floorf(cx * 0.25f);
        float c1 = floorf(cy * 0.25f);
        float w = x2 - x1, h = y2 - y1;
        float sigma = fmaxf(w, h) * 0.25f;     // sizes.max(-1)/DS
        BoxParam p;
        p.ci0 = c0; p.ci1 = c1;
        p.inv2sig = 1.0f / (2.0f * sigma);
        p.cls = gtc[t];
        bp[t] = p;
    }
    if (t == 0) out[OFF_PFL] = 0.0f;
    __syncthreads();
    if (t < NB) {
        int b = t;
        int base = b * NM;
        int cnt[NC + 1];
        for (int c = 0; c <= NC; ++c) cnt[c] = 0;
        for (int m = 0; m < NM; ++m) cnt[bp[base + m].cls + 1]++;
        for (int c = 0; c < NC; ++c) cnt[c + 1] += cnt[c];
        int* st = csr_start + b * (NC + 1);
        for (int c = 0; c <= NC; ++c) st[c] = cnt[c];
        int pos[NC];
        for (int c = 0; c < NC; ++c) pos[c] = cnt[c];
        for (int m = 0; m < NM; ++m) {
            int c = bp[base + m].cls;
            csr_order[base + pos[c]++] = m;
        }
    }
}

// ---------------- kernel 2: fused NMS + gt_hm + focal ----------------
// tile = 2 rows x 128 cols, 256 threads. Classes split across G=2^lgG groups.
// Separable 3x3 max: 3 vertical loads/lane + shuffles; interior column
// boundary (j==63/64) patched via exec-masked 3-load on 2 lanes/wave.
// 1-deep software prefetch of next class's loads.
__launch_bounds__(256)
__global__ void main_kernel(const float* __restrict__ hm,
                            const BoxParam* __restrict__ bp,
                            const int* __restrict__ csr_start,
                            const int* __restrict__ csr_order,
                            float* __restrict__ pbest, int* __restrict__ pidx,
                            float* __restrict__ out, int lgG) {
    int blk = blockIdx.x;
    int G = 1 << lgG;
    int g = blk & (G - 1);
    int t2 = blk >> lgG;
    int b = t2 >> 6;
    int i0 = (t2 & 63) << 1;
    int tid = threadIdx.x;
    int j = tid & 127;
    int row = tid >> 7;
    int i = i0 + row;
    int ncl = NC >> lgG;
    int c0 = g * ncl;

    __shared__ int   s_start[NC + 1];
    __shared__ float s_box[NM][3];
    __shared__ int   s_ord[NM];
    for (int k = tid; k < NC + 1; k += 256) s_start[k] = csr_start[b * (NC + 1) + k];
    if (tid < NM) {
        BoxParam p = bp[b * NM + tid];
        s_box[tid][0] = p.ci0; s_box[tid][1] = p.ci1; s_box[tid][2] = p.inv2sig;
        s_ord[tid] = csr_order[b * NM + tid];
    }
    __syncthreads();

    const float fi = (float)i, fj = (float)j;
    int iu  = (i > 0) ? i - 1 : 0;
    int idn = (i < HH - 1) ? i + 1 : HH - 1;
    int offc = i * WW + j, offu = iu * WW + j, offd = idn * WW + j;

    // interior column boundary lanes
    bool e_lo = (j == 64);   // lane 0 of second half-wave: needs col 63
    bool e_hi = (j == 63);   // lane 63 of first half-wave: needs col 64
    bool edge = e_lo || e_hi;
    int ed = e_lo ? -1 : 1;

    const float* plane = hm + ((size_t)b * NC + c0) * HW;
    float* gp = out + OFF_GTHM + ((size_t)b * NC + c0) * HW;

    float best = -1.0f; int bc = 0; float facc = 0.0f;

    // initial loads (class c0)
    float h = plane[offc], up = plane[offu], dn = plane[offd];
    float eh = 0.f, eu = 0.f, edv = 0.f;
    if (edge) { eh = plane[offc + ed]; eu = plane[offu + ed]; edv = plane[offd + ed]; }

    for (int cc = 0; cc < ncl; ++cc) {
        // prefetch next class
        float hn = 0.f, un = 0.f, dnn = 0.f, ehn = 0.f, eun = 0.f, edn2 = 0.f;
        if (cc + 1 < ncl) {
            const float* pn = plane + HW;
            hn = pn[offc]; un = pn[offu]; dnn = pn[offd];
            if (edge) { ehn = pn[offc + ed]; eun = pn[offu + ed]; edn2 = pn[offd + ed]; }
        }

        float vmx = fmax3(up, h, dn);
        float ev  = fmax3(eu, eh, edv);   // garbage on non-edge lanes, never selected
        float lf = __shfl_up(vmx, 1);
        float rt = __shfl_down(vmx, 1);
        if (j == 0)   lf = vmx; else if (e_lo) lf = ev;
        if (j == 127) rt = vmx; else if (e_hi) rt = ev;
        float mx = fmax3(lf, vmx, rt);

        float p = (h >= mx) ? h : 0.0f;
        if (p > best) { best = p; bc = c0 + cc; }

        // gt_hm: max over boxes of this class
        float gval = 0.0f;
        int c = c0 + cc;
        int s0 = s_start[c], s1 = s_start[c + 1];
        for (int k = s0; k < s1; ++k) {
            int m = s_ord[k];
            float d0 = fi - s_box[m][0];
            float d1 = fj - s_box[m][1];
            gval = fmaxf(gval, __expf(-(d0 * d0 + d1 * d1) * s_box[m][2]));
        }
        gp[offc] = gval;

        // focal
        float oh = 1.0f - h;
        float om = 1.0f - gval;
        float om2 = om * om, g2 = gval * gval;
        facc += (om2 * om2) * h * h * __logf(oh) + (g2 * g2) * oh * oh * __logf(h);

        plane += HW; gp += HW;
        h = hn; up = un; dn = dnn; eh = ehn; eu = eun; edv = edn2;
    }

    int pix = (b * HH + i) * WW + j;
    pbest[(size_t)g * NPIX + pix] = best;
    pidx [(size_t)g * NPIX + pix] = bc;

    #pragma unroll
    for (int off = 32; off > 0; off >>= 1) facc += __shfl_down(facc, off);
    __shared__ float s_red[4];
    if ((tid & 63) == 0) s_red[tid >> 6] = facc;
    __syncthreads();
    if (tid == 0)
        atomicAdd(out + OFF_PFL, -(s_red[0] + s_red[1] + s_red[2] + s_red[3]));
}

// ---------------- kernel 3: combine partials + bbox decode ----------------
__global__ void combine_kernel(const float* __restrict__ pbest, const int* __restrict__ pidx,
                               const float* __restrict__ sz, const float* __restrict__ osr,
                               float* __restrict__ out, int G) {
    int pix = blockIdx.x * 256 + threadIdx.x;
    float best = -1.0f; int bi = 0;
    for (int g = 0; g < G; ++g) {
        float v = pbest[(size_t)g * NPIX + pix];
        int ix = pidx[(size_t)g * NPIX + pix];
        if (v > best) { best = v; bi = ix; }   // groups in class order -> first-max kept
    }
    out[OFF_VALUES + pix] = best;
    out[OFF_IDXS + pix]   = (float)bi;
    out[OFF_KEEP + pix]   = (best > 0.0f) ? 1.0f : 0.0f;

    int b = pix >> 14, ij = pix & 16383;
    float fi = (float)(ij >> 7), fj = (float)(ij & 127);
    const float* szb = sz + (size_t)b * 2 * HW;
    const float* osb = osr + (size_t)b * 2 * HW;
    float s0v = szb[ij], s1v = szb[HW + ij];
    float o0 = osb[ij],  o1 = osb[HW + ij];
    float cx = fi * 4.0f + o0, cy = fj * 4.0f + o1;
    float4 bb;
    bb.x = fminf(fmaxf(cx - s0v * 0.5f, 0.0f), IMG);
    bb.y = fminf(fmaxf(cy - s1v * 0.5f, 0.0f), IMG);
    bb.z = fminf(fmaxf(cx + s0v * 0.5f, 0.0f), IMG);
    bb.w = fminf(fmaxf(cy + s1v * 0.5f, 0.0f), IMG);
    reinterpret_cast<float4*>(out + OFF_BBOX)[pix] = bb;
}

// ---------------- kernel 4: size / offset losses at center cells ----------------
__global__ void loss_kernel(const float* __restrict__ gtb, const float* __restrict__ sz,
                            const float* __restrict__ osr, float* __restrict__ out) {
    int t = threadIdx.x;
    int b = t >> 5, m = t & 31;
    __shared__ int s_ci[NB * NM];
    const float* g = gtb + t * 4;
    float x1 = g[0], y1 = g[1], x2 = g[2], y2 = g[3];
    float cx = (x1 + x2) * 0.5f, cy = (y1 + y2) * 0.5f;
    float c0f = floorf(cx * 0.25f), c1f = floorf(cy * 0.25f);
    int ci0 = (int)c0f, ci1 = (int)c1f;
    s_ci[t] = ci0 * WW + ci1;
    __syncthreads();

    bool winner = true;
    int mycell = s_ci[t];
    for (int m2 = m + 1; m2 < NM; ++m2)
        if (s_ci[b * NM + m2] == mycell) { winner = false; break; }

    float nloc = 0.0f, szs = 0.0f, oss = 0.0f;
    if (winner) {
        nloc = 1.0f;
        float w = x2 - x1, h = y2 - y1;
        float offx = cx * 0.25f - c0f, offy = cy * 0.25f - c1f;
        size_t pb = (size_t)b * 2 * HW + (size_t)ci0 * WW + ci1;
        float ps0 = sz[pb], ps1 = sz[pb + HW];
        float po0 = osr[pb], po1 = osr[pb + HW];
        szs = smooth_l1(ps0, w) + smooth_l1(ps1, h);
        oss = smooth_l1(po0, offx) + smooth_l1(po1, offy);
    }

    #pragma unroll
    for (int off = 32; off > 0; off >>= 1) {
        nloc += __shfl_down(nloc, off);
        szs  += __shfl_down(szs, off);
        oss  += __shfl_down(oss, off);
    }
    __shared__ float red[8][3];
    int wid = t >> 6;
    if ((t & 63) == 0) { red[wid][0] = nloc; red[wid][1] = szs; red[wid][2] = oss; }
    __syncthreads();
    if (t == 0) {
        float n = 0.0f, ss = 0.0f, os_ = 0.0f;
        for (int w2 = 0; w2 < 8; ++w2) { n += red[w2][0]; ss += red[w2][1]; os_ += red[w2][2]; }
        out[OFF_SZL] = ss / (2.0f * n) / n;
        out[OFF_OSL] = os_ / (2.0f * n) / n;
    }
}

extern "C" void kernel_launch(void* const* d_in, const int* in_sizes, int n_in,
                              void* d_out, int out_size, void* d_ws, size_t ws_size,
                              hipStream_t stream) {
    const float* hm  = (const float*)d_in[0];
    const float* sz  = (const float*)d_in[1];
    const float* osr = (const float*)d_in[2];
    const float* gtb = (const float*)d_in[3];
    const int*   gtc = (const int*)d_in[4];
    float* out = (float*)d_out;

    BoxParam* bp   = (BoxParam*)d_ws;                    // [0, 8192)
    int* csr_start = (int*)((char*)d_ws + 8192);         // 16*81*4 = 5184
    int* csr_order = (int*)((char*)d_ws + 13376);        // 512*4 = 2048  (ends 15424)

    // class-group split for occupancy: G=2 needs 16384 + 2*NPIX*8 bytes of ws
    int lgG = (ws_size >= (size_t)16384 + (size_t)2 * NPIX * 8) ? 1 : 0;
    int G = 1 << lgG;
    float* ws_best;
    int*   ws_idx;
    if (lgG > 0) {
        ws_best = (float*)((char*)d_ws + 16384);
        ws_idx  = (int*)((char*)d_ws + 16384 + (size_t)G * NPIX * 4);
    } else {
        ws_best = out + OFF_VALUES;           // in-place partials, combine rewrites
        ws_idx  = (int*)(out + OFF_IDXS);
    }

    setup_kernel<<<1, 512, 0, stream>>>(gtb, gtc, bp, csr_start, csr_order, out);
    main_kernel<<<NB * 64 * G, 256, 0, stream>>>(hm, bp, csr_start, csr_order,
                                                 ws_best, ws_idx, out, lgG);
    combine_kernel<<<NPIX / 256, 256, 0, stream>>>(ws_best, ws_idx, sz, osr, out, G);
    loss_kernel<<<1, 512, 0, stream>>>(gtb, sz, osr, out);
}

// Round 3
// 68.324 us; speedup vs baseline: 3.7330x; 1.3719x over previous
//
#include <hip/hip_runtime.h>
#include <math.h>

#define NB 16      // batch
#define NC 80      // classes
#define HH 128
#define WW 128
#define HW (HH*WW)
#define HW4 (HW/4)
#define NPIX (NB*HH*WW)   // 262144
#define NM 32      // boxes per batch
#define IMG 512.0f

// output layout (float offsets)
#define OFF_VALUES 0
#define OFF_IDXS   262144
#define OFF_BBOX   524288
#define OFF_KEEP   1572864
#define OFF_PFL    1835008
#define OFF_SZL    1835009
#define OFF_OSL    1835010
#define OFF_GTHM   1835011   // NOTE: ≡3 mod 4 floats -> gt_hm is NOT 16B aligned; scalar stores only

struct BoxParam { float ci0, ci1, inv2sig; int cls; };

__device__ __forceinline__ float smooth_l1(float p, float g) {
    float d = fabsf(p - g);
    return (d < 1.0f) ? 0.5f * d * d : d - 0.5f;
}
__device__ __forceinline__ float fmax3(float a, float b, float c) {
    return fmaxf(fmaxf(a, b), c);
}

// ---------------- kernel 1: box params + per-batch class CSR ----------------
__global__ void setup_kernel(const float* __restrict__ gtb, const int* __restrict__ gtc,
                             BoxParam* __restrict__ bp, int* __restrict__ csr_start,
                             int* __restrict__ csr_order, float* __restrict__ out) {
    int t = threadIdx.x;  // blockDim = 512
    if (t < NB * NM) {
        const float* g = gtb + t * 4;
        float x1 = g[0], y1 = g[1], x2 = g[2], y2 = g[3];
        float cx = (x1 + x2) * 0.5f, cy = (y1 + y2) * 0.5f;
        float c0 = floorf(cx * 0.25f);
        float c1 = floorf(cy * 0.25f);
        float w = x2 - x1, h = y2 - y1;
        float sigma = fmaxf(w, h) * 0.25f;     // sizes.max(-1)/DS
        BoxParam p;
        p.ci0 = c0; p.ci1 = c1;
        p.inv2sig = 1.0f / (2.0f * sigma);
        p.cls = gtc[t];
        bp[t] = p;
    }
    if (t == 0) out[OFF_PFL] = 0.0f;
    __syncthreads();
    if (t < NB) {
        int b = t;
        int base = b * NM;
        int cnt[NC + 1];
        for (int c = 0; c <= NC; ++c) cnt[c] = 0;
        for (int m = 0; m < NM; ++m) cnt[bp[base + m].cls + 1]++;
        for (int c = 0; c < NC; ++c) cnt[c + 1] += cnt[c];
        int* st = csr_start + b * (NC + 1);
        for (int c = 0; c <= NC; ++c) st[c] = cnt[c];
        int pos[NC];
        for (int c = 0; c < NC; ++c) pos[c] = cnt[c];
        for (int m = 0; m < NM; ++m) {
            int c = bp[base + m].cls;
            csr_order[base + pos[c]++] = m;
        }
    }
}

// ---------------- kernel 2: fused NMS + gt_hm + focal, 4 px/lane ----------------
// tile = 8 rows x 128 cols (1024 px), 256 threads, each lane owns a float4 (4 cols).
// Half-wave (32 lanes) = one full row -> only lane-boundary clamps for 3x3 max.
__launch_bounds__(256)
__global__ void main_kernel(const float* __restrict__ hm,
                            const BoxParam* __restrict__ bp,
                            const int* __restrict__ csr_start,
                            const int* __restrict__ csr_order,
                            float* __restrict__ pbest, int* __restrict__ pidx,
                            float* __restrict__ out, int lgG) {
    int blk = blockIdx.x;
    int G = 1 << lgG;
    int g = blk & (G - 1);
    int t2 = blk >> lgG;           // 0 .. NB*16-1
    int b = t2 >> 4;
    int i0 = (t2 & 15) << 3;       // 8 rows / tile
    int tid = threadIdx.x;
    int row = tid >> 5;            // 0..7
    int jb  = (tid & 31) << 2;     // col base, multiple of 4
    int i = i0 + row;
    int ncl = NC >> lgG;
    int c0 = g * ncl;

    __shared__ int   s_start[NC + 1];
    __shared__ float s_box[NM][3];
    __shared__ int   s_ord[NM];
    for (int k = tid; k < NC + 1; k += 256) s_start[k] = csr_start[b * (NC + 1) + k];
    if (tid < NM) {
        BoxParam p = bp[b * NM + tid];
        s_box[tid][0] = p.ci0; s_box[tid][1] = p.ci1; s_box[tid][2] = p.inv2sig;
        s_ord[tid] = csr_order[b * NM + tid];
    }
    __syncthreads();

    const float fi = (float)i, fjb = (float)jb;
    int iu  = (i > 0) ? i - 1 : 0;
    int idn = (i < HH - 1) ? i + 1 : HH - 1;
    size_t base = ((size_t)b * NC + c0) * HW;

    const float4* pC = (const float4*)(hm + base + i   * WW + jb);
    const float4* pU = (const float4*)(hm + base + iu  * WW + jb);
    const float4* pD = (const float4*)(hm + base + idn * WW + jb);
    float* gp = out + OFF_GTHM + base + i * WW + jb;   // 4B-aligned only

    int lane31 = tid & 31;        // position within the row's 32 lanes
    bool clampL = (lane31 == 0);
    bool clampR = (lane31 == 31);

    float bestv[4] = {-1.f, -1.f, -1.f, -1.f};
    int   bestc[4] = {0, 0, 0, 0};
    float facc = 0.0f;

    auto process = [&](float4 cC, float4 cU, float4 cD, int c, float* gpc) {
        float h[4] = {cC.x, cC.y, cC.z, cC.w};
        float vm[4];
        vm[0] = fmax3(cU.x, h[0], cD.x);
        vm[1] = fmax3(cU.y, h[1], cD.y);
        vm[2] = fmax3(cU.z, h[2], cD.z);
        vm[3] = fmax3(cU.w, h[3], cD.w);
        float left  = __shfl_up(vm[3], 1);
        float right = __shfl_down(vm[0], 1);
        if (clampL) left  = vm[0];
        if (clampR) right = vm[3];
        float mx[4];
        mx[0] = fmax3(left,  vm[0], vm[1]);
        mx[1] = fmax3(vm[0], vm[1], vm[2]);
        mx[2] = fmax3(vm[1], vm[2], vm[3]);
        mx[3] = fmax3(vm[2], vm[3], right);
        #pragma unroll
        for (int k = 0; k < 4; ++k) {
            float p = (h[k] >= mx[k]) ? h[k] : 0.0f;
            if (p > bestv[k]) { bestv[k] = p; bestc[k] = c; }
        }

        int s0 = s_start[c], s1 = s_start[c + 1];
        if (s0 == s1) {
            // no boxes of this class in this batch: gt = 0 exactly
            __builtin_nontemporal_store(0.0f, gpc + 0);
            __builtin_nontemporal_store(0.0f, gpc + 1);
            __builtin_nontemporal_store(0.0f, gpc + 2);
            __builtin_nontemporal_store(0.0f, gpc + 3);
            #pragma unroll
            for (int k = 0; k < 4; ++k)
                facc += h[k] * h[k] * __logf(1.0f - h[k]);
        } else {
            float gv[4] = {0.f, 0.f, 0.f, 0.f};
            for (int kk = s0; kk < s1; ++kk) {
                int m = s_ord[kk];
                float d0 = fi - s_box[m][0];
                float nis = -s_box[m][2];
                float dj = fjb - s_box[m][1];
                float e = d0 * d0;
                #pragma unroll
                for (int k = 0; k < 4; ++k) {
                    float d1 = dj + (float)k;
                    gv[k] = fmaxf(gv[k], __expf((e + d1 * d1) * nis));
                }
            }
            __builtin_nontemporal_store(gv[0], gpc + 0);
            __builtin_nontemporal_store(gv[1], gpc + 1);
            __builtin_nontemporal_store(gv[2], gpc + 2);
            __builtin_nontemporal_store(gv[3], gpc + 3);
            #pragma unroll
            for (int k = 0; k < 4; ++k) {
                float hk = h[k], ohk = 1.0f - hk;
                float gk = gv[k], omk = 1.0f - gk;
                float om2 = omk * omk, g2 = gk * gk;
                facc += (om2 * om2) * hk * hk * __logf(ohk)
                      + (g2 * g2) * ohk * ohk * __logf(hk);
            }
        }
    };

    float4 cC = *pC, cU = *pU, cD = *pD;
    for (int cc = 0; cc < ncl - 1; ++cc) {
        float4 nC = pC[HW4], nU = pU[HW4], nD = pD[HW4];   // prefetch next class
        process(cC, cU, cD, c0 + cc, gp);
        pC += HW4; pU += HW4; pD += HW4; gp += HW;
        cC = nC; cU = nU; cD = nD;
    }
    process(cC, cU, cD, c0 + ncl - 1, gp);

    int pixbase = (b * HH + i) * WW + jb;     // multiple of 4
    float4 bsv = {bestv[0], bestv[1], bestv[2], bestv[3]};
    int4   bci = {bestc[0], bestc[1], bestc[2], bestc[3]};
    *(float4*)(pbest + (size_t)g * NPIX + pixbase) = bsv;
    *(int4*)  (pidx  + (size_t)g * NPIX + pixbase) = bci;

    #pragma unroll
    for (int off = 32; off > 0; off >>= 1) facc += __shfl_down(facc, off);
    __shared__ float s_red[4];
    if ((tid & 63) == 0) s_red[tid >> 6] = facc;
    __syncthreads();
    if (tid == 0)
        atomicAdd(out + OFF_PFL, -(s_red[0] + s_red[1] + s_red[2] + s_red[3]));
}

// ---------------- kernel 3: combine partials + bbox decode, 4 px/thread ----------------
__global__ void combine_kernel(const float* __restrict__ pbest, const int* __restrict__ pidx,
                               const float* __restrict__ sz, const float* __restrict__ osr,
                               float* __restrict__ out, int G) {
    int p4 = blockIdx.x * 256 + threadIdx.x;   // covers px [4*p4, 4*p4+3]
    int px = p4 << 2;
    float bv[4] = {-1.f, -1.f, -1.f, -1.f};
    int   bi[4] = {0, 0, 0, 0};
    for (int g = 0; g < G; ++g) {
        float4 v = *(const float4*)(pbest + (size_t)g * NPIX + px);
        int4  ix = *(const int4*)  (pidx  + (size_t)g * NPIX + px);
        float vv[4] = {v.x, v.y, v.z, v.w};
        int   ii[4] = {ix.x, ix.y, ix.z, ix.w};
        #pragma unroll
        for (int k = 0; k < 4; ++k)
            if (vv[k] > bv[k]) { bv[k] = vv[k]; bi[k] = ii[k]; }  // class-ordered groups: first max wins
    }
    float4 vals = {bv[0], bv[1], bv[2], bv[3]};
    float4 idxf = {(float)bi[0], (float)bi[1], (float)bi[2], (float)bi[3]};
    float4 keep = {bv[0] > 0.f ? 1.f : 0.f, bv[1] > 0.f ? 1.f : 0.f,
                   bv[2] > 0.f ? 1.f : 0.f, bv[3] > 0.f ? 1.f : 0.f};
    *(float4*)(out + OFF_VALUES + px) = vals;
    *(float4*)(out + OFF_IDXS + px)   = idxf;
    *(float4*)(out + OFF_KEEP + px)   = keep;

    int b = px >> 14, ij = px & 16383;
    float fi = (float)(ij >> 7), fjb = (float)(ij & 127);
    const float* szb = sz  + (size_t)b * 2 * HW;
    const float* osb = osr + (size_t)b * 2 * HW;
    float4 s0v = *(const float4*)(szb + ij);
    float4 s1v = *(const float4*)(szb + HW + ij);
    float4 o0v = *(const float4*)(osb + ij);
    float4 o1v = *(const float4*)(osb + HW + ij);
    float s0a[4] = {s0v.x, s0v.y, s0v.z, s0v.w};
    float s1a[4] = {s1v.x, s1v.y, s1v.z, s1v.w};
    float o0a[4] = {o0v.x, o0v.y, o0v.z, o0v.w};
    float o1a[4] = {o1v.x, o1v.y, o1v.z, o1v.w};
    #pragma unroll
    for (int k = 0; k < 4; ++k) {
        float cx = fi * 4.0f + o0a[k];
        float cy = (fjb + (float)k) * 4.0f + o1a[k];
        float4 bb;
        bb.x = fminf(fmaxf(cx - s0a[k] * 0.5f, 0.0f), IMG);
        bb.y = fminf(fmaxf(cy - s1a[k] * 0.5f, 0.0f), IMG);
        bb.z = fminf(fmaxf(cx + s0a[k] * 0.5f, 0.0f), IMG);
        bb.w = fminf(fmaxf(cy + s1a[k] * 0.5f, 0.0f), IMG);
        reinterpret_cast<float4*>(out + OFF_BBOX)[px + k] = bb;
    }
}

// ---------------- kernel 4: size / offset losses at center cells ----------------
__global__ void loss_kernel(const float* __restrict__ gtb, const float* __restrict__ sz,
                            const float* __restrict__ osr, float* __restrict__ out) {
    int t = threadIdx.x;
    int b = t >> 5, m = t & 31;
    __shared__ int s_ci[NB * NM];
    const float* g = gtb + t * 4;
    float x1 = g[0], y1 = g[1], x2 = g[2], y2 = g[3];
    float cx = (x1 + x2) * 0.5f, cy = (y1 + y2) * 0.5f;
    float c0f = floorf(cx * 0.25f), c1f = floorf(cy * 0.25f);
    int ci0 = (int)c0f, ci1 = (int)c1f;
    s_ci[t] = ci0 * WW + ci1;
    __syncthreads();

    bool winner = true;
    int mycell = s_ci[t];
    for (int m2 = m + 1; m2 < NM; ++m2)
        if (s_ci[b * NM + m2] == mycell) { winner = false; break; }

    float nloc = 0.0f, szs = 0.0f, oss = 0.0f;
    if (winner) {
        nloc = 1.0f;
        float w = x2 - x1, h = y2 - y1;
        float offx = cx * 0.25f - c0f, offy = cy * 0.25f - c1f;
        size_t pb = (size_t)b * 2 * HW + (size_t)ci0 * WW + ci1;
        float ps0 = sz[pb], ps1 = sz[pb + HW];
        float po0 = osr[pb], po1 = osr[pb + HW];
        szs = smooth_l1(ps0, w) + smooth_l1(ps1, h);
        oss = smooth_l1(po0, offx) + smooth_l1(po1, offy);
    }

    #pragma unroll
    for (int off = 32; off > 0; off >>= 1) {
        nloc += __shfl_down(nloc, off);
        szs  += __shfl_down(szs, off);
        oss  += __shfl_down(oss, off);
    }
    __shared__ float red[8][3];
    int wid = t >> 6;
    if ((t & 63) == 0) { red[wid][0] = nloc; red[wid][1] = szs; red[wid][2] = oss; }
    __syncthreads();
    if (t == 0) {
        float n = 0.0f, ss = 0.0f, os_ = 0.0f;
        for (int w2 = 0; w2 < 8; ++w2) { n += red[w2][0]; ss += red[w2][1]; os_ += red[w2][2]; }
        out[OFF_SZL] = ss / (2.0f * n) / n;
        out[OFF_OSL] = os_ / (2.0f * n) / n;
    }
}

extern "C" void kernel_launch(void* const* d_in, const int* in_sizes, int n_in,
                              void* d_out, int out_size, void* d_ws, size_t ws_size,
                              hipStream_t stream) {
    const float* hm  = (const float*)d_in[0];
    const float* sz  = (const float*)d_in[1];
    const float* osr = (const float*)d_in[2];
    const float* gtb = (const float*)d_in[3];
    const int*   gtc = (const int*)d_in[4];
    float* out = (float*)d_out;

    BoxParam* bp   = (BoxParam*)d_ws;                    // [0, 8192)
    int* csr_start = (int*)((char*)d_ws + 8192);         // 16*81*4 = 5184
    int* csr_order = (int*)((char*)d_ws + 13376);        // 512*4 = 2048  (ends 15424)

    size_t need4 = 16384 + (size_t)4 * NPIX * 8;
    size_t need2 = 16384 + (size_t)2 * NPIX * 8;
    int lgG = (ws_size >= need4) ? 2 : (ws_size >= need2) ? 1 : 0;
    int G = 1 << lgG;
    float* ws_best;
    int*   ws_idx;
    if (lgG > 0) {
        ws_best = (float*)((char*)d_ws + 16384);
        ws_idx  = (int*)((char*)d_ws + 16384 + (size_t)G * NPIX * 4);
    } else {
        ws_best = out + OFF_VALUES;           // in-place partials, combine rewrites
        ws_idx  = (int*)(out + OFF_IDXS);
    }

    setup_kernel<<<1, 512, 0, stream>>>(gtb, gtc, bp, csr_start, csr_order, out);
    main_kernel<<<NB * 16 * G, 256, 0, stream>>>(hm, bp, csr_start, csr_order,
                                                 ws_best, ws_idx, out, lgG);
    combine_kernel<<<NPIX / 4 / 256, 256, 0, stream>>>(ws_best, ws_idx, sz, osr, out, G);
    loss_kernel<<<1, 512, 0, stream>>>(gtb, sz, osr, out);
}